// Round 7
// baseline (98.224 us; speedup 1.0000x reference)
//
#include <hip/hip_runtime.h>
#include <math.h>

#define T_SEQ 2048
#define NH    16
#define HD    64
#define DIM   1024
#define WIN   256
#define REP   6   // proj GEMM repetitions: instrumentation (counters visibility).

typedef __attribute__((ext_vector_type(4))) float f32x4;
typedef __attribute__((ext_vector_type(8))) short s16x8;
typedef unsigned short u16;

static __device__ __forceinline__ u16 f2bf(float f) {
    unsigned u = __builtin_bit_cast(unsigned, f);
    u += 0x7fff + ((u >> 16) & 1);   // RNE; inputs finite
    return (u16)(u >> 16);
}

static __device__ __forceinline__ int fV(int d) { return (d & 7) ^ ((d >> 3) & 7); }

static __device__ __forceinline__ void gload16(const void* g, void* l) {
    __builtin_amdgcn_global_load_lds(
        (const __attribute__((address_space(1))) unsigned int*)g,
        (__attribute__((address_space(3))) unsigned int*)l, 16, 0, 0);
}

// ---------------------------------------------------------------------------
// Fused prep kernel (unchanged from round 6).
// blocks [0,256): W transpose+bf16. blocks [256,768): attention.
// ---------------------------------------------------------------------------
__global__ __launch_bounds__(256) void prep_kernel(const float* __restrict__ W,
                                                   u16* __restrict__ Wt,
                                                   const float* __restrict__ qg,
                                                   const float* __restrict__ kg,
                                                   const float* __restrict__ vg,
                                                   u16* __restrict__ y) {
    __shared__ __align__(16) char smem[4 * 16 * 128 + 2 * 64 * 128];  // 24KB
    const int bid = (int)blockIdx.x;
    const int t   = threadIdx.x;

    if (bid < 256) {
        float(*sT)[69] = (float(*)[69])smem;
        const int k0 = (bid & 15) * 64;
        const int n0 = (bid >> 4) * 64;
#pragma unroll
        for (int i = 0; i < 4; ++i) {
            const int idx = i * 256 + t;
            const int kr = idx >> 4, c4 = (idx & 15) * 4;
            float4 v = *(const float4*)(W + (size_t)(k0 + kr) * DIM + n0 + c4);
            sT[kr][c4] = v.x; sT[kr][c4 + 1] = v.y; sT[kr][c4 + 2] = v.z; sT[kr][c4 + 3] = v.w;
        }
        __syncthreads();
#pragma unroll
        for (int i = 0; i < 2; ++i) {
            const int idx = i * 256 + t;
            const int nr = idx >> 3, ch = (idx & 7) * 8;
            s16x8 o;
#pragma unroll
            for (int e = 0; e < 8; ++e) o[e] = f2bf(sT[ch + e][nr]);
            *(s16x8*)(Wt + (size_t)(n0 + nr) * DIM + k0 + ch) = o;
        }
        return;
    }

    char* sK  = smem;
    char* sV  = smem + 64 * 128;
    char* sPb = smem + 2 * 64 * 128;

    const int ab   = bid - 256;
    const int lane = t & 63;
    const int w    = t >> 6;
    const int q0   = (ab & 31) * 64;
    const int h    = ab >> 5;
    const size_t headBase = (size_t)h * T_SEQ * HD;

    const int lr = lane & 15;
    const int lg = lane >> 4;

    s16x8 qf[2];
    {
        const float* qrow = qg + headBase + (size_t)(q0 + w * 16 + lr) * HD + lg * 8;
#pragma unroll
        for (int s = 0; s < 2; ++s) {
            float4 a = *(const float4*)(qrow + 32 * s);
            float4 b = *(const float4*)(qrow + 32 * s + 4);
            s16x8 f;
            f[0] = f2bf(a.x); f[1] = f2bf(a.y); f[2] = f2bf(a.z); f[3] = f2bf(a.w);
            f[4] = f2bf(b.x); f[5] = f2bf(b.y); f[6] = f2bf(b.z); f[7] = f2bf(b.w);
            qf[s] = f;
        }
    }

    f32x4 o[4];
#pragma unroll
    for (int i = 0; i < 4; ++i) o[i] = (f32x4){0.f, 0.f, 0.f, 0.f};
    float lsum[4] = {0.f, 0.f, 0.f, 0.f};

    int lo = q0 - (WIN - 1);
    if (lo < 0) lo = 0;
    const int kc0 = lo & ~63;

    const int srow = t >> 2;
    const int sd0  = (t & 3) * 16;

    for (int kc = kc0; kc <= q0; kc += 64) {
        __syncthreads();
        {
            const float* ksrc = kg + headBase + (size_t)(kc + srow) * HD + sd0;
            float4 k0 = *(const float4*)(ksrc);
            float4 k1 = *(const float4*)(ksrc + 4);
            float4 k2 = *(const float4*)(ksrc + 8);
            float4 k3 = *(const float4*)(ksrc + 12);
            s16x8 c0, c1;
            c0[0] = f2bf(k0.x); c0[1] = f2bf(k0.y); c0[2] = f2bf(k0.z); c0[3] = f2bf(k0.w);
            c0[4] = f2bf(k1.x); c0[5] = f2bf(k1.y); c0[6] = f2bf(k1.z); c0[7] = f2bf(k1.w);
            c1[0] = f2bf(k2.x); c1[1] = f2bf(k2.y); c1[2] = f2bf(k2.z); c1[3] = f2bf(k2.w);
            c1[4] = f2bf(k3.x); c1[5] = f2bf(k3.y); c1[6] = f2bf(k3.z); c1[7] = f2bf(k3.w);
            const int swz = (srow & 7) << 4;
            *(s16x8*)(sK + srow * 128 + ((sd0 * 2) ^ swz))      = c0;
            *(s16x8*)(sK + srow * 128 + ((sd0 * 2 + 16) ^ swz)) = c1;

            const float* vsrc = vg + headBase + (size_t)(kc + srow) * HD + sd0;
            float4 v0 = *(const float4*)(vsrc);
            float4 v1 = *(const float4*)(vsrc + 4);
            float4 v2 = *(const float4*)(vsrc + 8);
            float4 v3 = *(const float4*)(vsrc + 12);
            float vv[16] = {v0.x, v0.y, v0.z, v0.w, v1.x, v1.y, v1.z, v1.w,
                            v2.x, v2.y, v2.z, v2.w, v3.x, v3.y, v3.z, v3.w};
#pragma unroll
            for (int e = 0; e < 16; ++e) {
                const int d = sd0 + e;
                *(u16*)(sV + d * 128 + ((srow * 2) ^ (fV(d) << 4))) = f2bf(vv[e]);
            }
        }
        __syncthreads();

        char* pw = sPb + w * 16 * 128;
#pragma unroll
        for (int kt = 0; kt < 4; ++kt) {
            const int krow = kt * 16 + lr;
            const int kswz = (krow & 7) << 4;
            s16x8 kf0 = *(const s16x8*)(sK + krow * 128 + ((lg * 16) ^ kswz));
            s16x8 kf1 = *(const s16x8*)(sK + krow * 128 + ((lg * 16 + 64) ^ kswz));
            f32x4 s = (f32x4){0.f, 0.f, 0.f, 0.f};
            s = __builtin_amdgcn_mfma_f32_16x16x32_bf16(qf[0], kf0, s, 0, 0, 0);
            s = __builtin_amdgcn_mfma_f32_16x16x32_bf16(qf[1], kf1, s, 0, 0, 0);
            const int key = kc + kt * 16 + lr;
#pragma unroll
            for (int r = 0; r < 4; ++r) {
                const int qrow = q0 + w * 16 + lg * 4 + r;
                float pv = 0.f;
                if (key <= qrow && key > qrow - WIN) pv = __expf(s[r] * 0.125f);
                lsum[r] += pv;
                const int prow = lg * 4 + r;
                *(u16*)(pw + prow * 128 + ((kt * 32 + lr * 2) ^ ((prow & 7) << 4))) = f2bf(pv);
            }
        }

        s16x8 pf0 = *(const s16x8*)(pw + lr * 128 + ((lg * 16) ^ ((lr & 7) << 4)));
        s16x8 pf1 = *(const s16x8*)(pw + lr * 128 + ((lg * 16 + 64) ^ ((lr & 7) << 4)));
#pragma unroll
        for (int td = 0; td < 4; ++td) {
            const int drow = td * 16 + lr;
            const int vswz = fV(drow) << 4;
            s16x8 vf0 = *(const s16x8*)(sV + drow * 128 + ((lg * 16) ^ vswz));
            s16x8 vf1 = *(const s16x8*)(sV + drow * 128 + ((lg * 16 + 64) ^ vswz));
            o[td] = __builtin_amdgcn_mfma_f32_16x16x32_bf16(pf0, vf0, o[td], 0, 0, 0);
            o[td] = __builtin_amdgcn_mfma_f32_16x16x32_bf16(pf1, vf1, o[td], 0, 0, 0);
        }
    }

#pragma unroll
    for (int m = 1; m < 16; m <<= 1) {
#pragma unroll
        for (int r = 0; r < 4; ++r) lsum[r] += __shfl_xor(lsum[r], m, 64);
    }
    float rl[4];
#pragma unroll
    for (int r = 0; r < 4; ++r) rl[r] = 1.f / lsum[r];
#pragma unroll
    for (int td = 0; td < 4; ++td)
#pragma unroll
        for (int r = 0; r < 4; ++r)
            y[(size_t)(q0 + w * 16 + lg * 4 + r) * DIM + h * HD + td * 16 + lr] =
                f2bf(o[td][r] * rl[r]);
}

// ---------------------------------------------------------------------------
// proj: out = y @ W. BM=BN=128, BK=64, 4 waves (2x2), wave-tile 64x64
// (32 FLOP per LDS-read byte -- above the 26.4 break-even; the only geometry
// not LDS-read-bound). Triple-buffered counted-vmcnt pipeline:
//   STAGE(t+2) ; vmcnt(16) ; s_barrier ; ds_read+MFMA(setprio) ; s_barrier
// grid = 128 blocks, XCD-chunked swizzle (A 512KB + B 2MB = 2.5MB/XCD L2).
// REP=6 repetitions (re-init acc each rep; identical deterministic output)
// so the dispatch exceeds the ~40us fill kernels and its counters surface.
// ---------------------------------------------------------------------------
__global__ __launch_bounds__(256) void proj_kernel(const u16* __restrict__ A,
                                                   const u16* __restrict__ Bt,
                                                   float* __restrict__ out) {
    __shared__ __align__(16) char sA[3][128 * 128];  // [m][k] bf16, 16KB/buf
    __shared__ __align__(16) char sB[3][128 * 128];  // [n][k] bf16, 16KB/buf

    const int t    = threadIdx.x;
    const int lane = t & 63;
    const int w    = t >> 6;
    const int wr   = w >> 1, wc = w & 1;
    const int lr   = lane & 15, lg = lane >> 4;

    // XCD-chunked bijective swizzle (nwg=128, 8 XCDs, q=16):
    // each XCD: 2 M-panels x 8 N-panels.
    const int id   = (int)blockIdx.x;
    const int wgid = (id & 7) * 16 + (id >> 3);
    const int m0   = (wgid >> 3) * 128;   // 16 M-panels
    const int n0   = (wgid & 7) * 128;    // 8 N-panels

    // staging: pass pi = p*4+w covers rows [pi*8, pi*8+8); lane -> row pi*8+(lane>>3),
    // chunk lane&7. LDS dest linear (wave-uniform base + lane*16).
    const int sRow = lane >> 3;
    const int sCh  = lane & 7;

#define STAGE(buf, k0)                                                                 \
    do {                                                                               \
        _Pragma("unroll") for (int p = 0; p < 4; ++p) {                                \
            const int pi  = p * 4 + w;                                                 \
            const int row = pi * 8 + sRow;                                             \
            gload16(A + (size_t)(m0 + row) * DIM + (k0) + ((sCh ^ (row & 7)) << 3),    \
                    sA[buf] + pi * 1024);                                              \
            gload16(Bt + (size_t)(n0 + row) * DIM + (k0) + ((sCh ^ (row & 7)) << 3),   \
                    sB[buf] + pi * 1024);                                              \
        }                                                                              \
    } while (0)

    f32x4 acc[4][4];

#pragma unroll 1
    for (int rep = 0; rep < REP; ++rep) {
#pragma unroll
        for (int i = 0; i < 4; ++i)
#pragma unroll
            for (int j = 0; j < 4; ++j) acc[i][j] = (f32x4){0.f, 0.f, 0.f, 0.f};

        STAGE(0, 0);
        STAGE(1, 64);

#pragma unroll
        for (int kt = 0; kt < DIM / 64; ++kt) {
            const int cur  = kt % 3;
            const int nxt  = (kt + 2) % 3;
            const int knxt = ((kt + 2) & 15) * 64;  // tail wraps: stale, harmless

            STAGE(nxt, knxt);                       // dest buf's prior writes landed
                                                    // (iter kt-1's vmcnt) and reads
                                                    // done (iter kt-1's end barrier)
            asm volatile("s_waitcnt vmcnt(16)" ::: "memory");  // own tile-kt landed
            __builtin_amdgcn_s_barrier();           // => ALL waves' tile-kt landed

            s16x8 af[2][4], bfr[2][4];
#pragma unroll
            for (int kh = 0; kh < 2; ++kh) {
#pragma unroll
                for (int mi = 0; mi < 4; ++mi) {
                    const int row = wr * 64 + mi * 16 + lr;
                    const int cc  = kh * 4 + lg;
                    af[kh][mi] = *(const s16x8*)(sA[cur] + row * 128 + ((cc ^ (row & 7)) << 4));
                }
#pragma unroll
                for (int ni = 0; ni < 4; ++ni) {
                    const int row = wc * 64 + ni * 16 + lr;
                    const int cc  = kh * 4 + lg;
                    bfr[kh][ni] = *(const s16x8*)(sB[cur] + row * 128 + ((cc ^ (row & 7)) << 4));
                }
            }
            __builtin_amdgcn_s_setprio(1);
#pragma unroll
            for (int kh = 0; kh < 2; ++kh)
#pragma unroll
                for (int mi = 0; mi < 4; ++mi)
#pragma unroll
                    for (int ni = 0; ni < 4; ++ni)
                        acc[mi][ni] = __builtin_amdgcn_mfma_f32_16x16x32_bf16(
                            af[kh][mi], bfr[kh][ni], acc[mi][ni], 0, 0, 0);
            __builtin_amdgcn_s_setprio(0);
            __builtin_amdgcn_s_barrier();           // buf[cur] reads done before
                                                    // next iter's STAGE overwrite
        }

        // rep boundary: drain so next rep's prologue STAGEs can't collide with
        // in-flight stale tail writes (WAW on buf 1/2).
        asm volatile("s_waitcnt vmcnt(0)" ::: "memory");
        __builtin_amdgcn_s_barrier();
    }
#undef STAGE

#pragma unroll
    for (int mi = 0; mi < 4; ++mi)
#pragma unroll
        for (int ni = 0; ni < 4; ++ni)
#pragma unroll
            for (int r = 0; r < 4; ++r)
                out[(size_t)(m0 + wr * 64 + mi * 16 + lg * 4 + r) * DIM +
                    n0 + wc * 64 + ni * 16 + lr] = acc[mi][ni][r];
}

extern "C" void kernel_launch(void* const* d_in, const int* in_sizes, int n_in,
                              void* d_out, int out_size, void* d_ws, size_t ws_size,
                              hipStream_t stream) {
    const float* q = (const float*)d_in[0];
    const float* k = (const float*)d_in[1];
    const float* v = (const float*)d_in[2];
    const float* W = (const float*)d_in[3];
    float* out = (float*)d_out;
    u16* y_bf = (u16*)d_ws;                       // (T, DIM) bf16 = 4MB
    u16* Wt   = (u16*)d_ws + (size_t)T_SEQ * DIM; // (DIM, DIM) bf16 = 2MB

    prep_kernel<<<768, 256, 0, stream>>>(W, Wt, q, k, v, y_bf);
    proj_kernel<<<128, 256, 0, stream>>>(y_bf, Wt, out);
}